// Round 10
// baseline (568.055 us; speedup 1.0000x reference)
//
#include <hip/hip_runtime.h>
#include <hip/hip_bf16.h>
#include <cstdint>
#include <cstddef>

// ---------------------------------------------------------------------------
// AutoEncoder: x[8192,1024] -> enc(1024->2048->2048->64, relu/relu/sigmoid)
//             -> dec(64->2048->2048->1024, relu/relu/none)
// R13 vs R12 (367.6us; gemm256 70.6us, MfmaUtil 40%):
//  - R10/R11/R12 = three schedules, identical 4950-5150 cyc/K-tile =
//    MFMA(2480)+LDS(2300) SERIALIZED. Cause: every variant has per-wave
//    program order reads(t)->MFMA(t) with a data dep; waves self-sync, LDS
//    storm then MFMA storm. Barrier placement is not the lever.
//  - Fix: software-pipeline fragment reads INTO the MFMA stream. Each MFMA
//    cluster is paired with reads it does NOT consume (af1/bfg1 of tile t
//    during q00/q10; af0/bfg0 of tile t+1 during q11/q01). The wave issues
//    ds_reads in the matrix-pipe-busy gaps -> LDS and MFMA overlap.
//  - Loop unrolled x2 with named ping-pong frag sets (rule #20: no runtime
//    indexing -> no scratch). One vmcnt(0)+barrier per K-tile. WAR audit:
//    all pre-BAR reads touch buf[t&1]; post-BAR DMA targets buf[(t+1)&1] ->
//    no cross-BAR in-flight-read hazard. Requires K%128==0 (1024/2048 ok).
//  - Frag VGPRs 96->72 declared (af0 x2, bfg0 x2, af1, bfg1 single).
// gemm256: 256x256 tile, BK=64, 512 thr / 8 waves; 24 b128 reads/wave/K-tile
// (minimum); XOR LDS swizzle via pre-swizzled global source (conflict-free,
// verified). e1/e2/d2 (83% of FLOPs); d1/e3/d3 on the R3 128^2 kernel.
// ---------------------------------------------------------------------------

typedef __bf16 bf16_t;
typedef bf16_t bf16x8 __attribute__((ext_vector_type(8)));
typedef bf16_t bf16x4 __attribute__((ext_vector_type(4)));
typedef float  floatx4 __attribute__((ext_vector_type(4)));

__device__ __forceinline__ void async_cp16(const bf16_t* gp, bf16_t* lp) {
    // global->LDS DMA, 16B/lane; LDS dest = wave-uniform base + lane*16
    __builtin_amdgcn_global_load_lds(
        (const __attribute__((address_space(1))) void*)gp,
        (__attribute__((address_space(3))) void*)lp, 16, 0, 0);
}

// ---------------------------------------------------------------------------
// Merged prep: x fp32->bf16 cast + 6 weight transpose+casts in one launch.
// ---------------------------------------------------------------------------
struct PrepArgs {
    const float* x; bf16_t* xb;
    const float* w[6]; bf16_t* t[6];
};

__device__ __forceinline__ void trans_tile(const float* __restrict__ in,
                                           bf16_t* __restrict__ out,
                                           int K, int N, int bx, int by,
                                           int tx, int ty,
                                           float (*tile)[33]) {
    const int n0 = bx * 32, k0 = by * 32;
#pragma unroll
    for (int i = 0; i < 32; i += 8)
        tile[ty + i][tx] = in[(size_t)(k0 + ty + i) * N + n0 + tx];
    __syncthreads();
#pragma unroll
    for (int i = 0; i < 32; i += 8)
        out[(size_t)(n0 + ty + i) * K + k0 + tx] = (bf16_t)tile[tx][ty + i];
}

__global__ __launch_bounds__(256) void prep(PrepArgs a) {
    __shared__ float tile[32][33];
    const int tx = threadIdx.x, ty = threadIdx.y;
    const int b = blockIdx.x;
    if (b < 8192) {                      // x cast: 8192*1024 elts, 4/thread
        const int i = (b * 256 + ty * 32 + tx) * 4;
        const float4 v = *(const float4*)(a.x + i);
        bf16x4 o;
        o[0] = (bf16_t)v.x; o[1] = (bf16_t)v.y;
        o[2] = (bf16_t)v.z; o[3] = (bf16_t)v.w;
        *(bf16x4*)(a.xb + i) = o;
        return;
    }
    int lb = b - 8192;
    if (lb < 2048)      { trans_tile(a.w[0], a.t[0], 1024, 2048, lb % 64, lb / 64, tx, ty, tile); return; }
    lb -= 2048;
    if (lb < 4096)      { trans_tile(a.w[1], a.t[1], 2048, 2048, lb % 64, lb / 64, tx, ty, tile); return; }
    lb -= 4096;
    if (lb < 128)       { trans_tile(a.w[2], a.t[2], 2048, 64,   lb % 2,  lb / 2,  tx, ty, tile); return; }
    lb -= 128;
    if (lb < 128)       { trans_tile(a.w[3], a.t[3], 64,   2048, lb % 64, lb / 64, tx, ty, tile); return; }
    lb -= 128;
    if (lb < 4096)      { trans_tile(a.w[4], a.t[4], 2048, 2048, lb % 64, lb / 64, tx, ty, tile); return; }
    lb -= 4096;
    trans_tile(a.w[5], a.t[5], 2048, 1024, lb % 32, lb / 32, tx, ty, tile);
}

// ---------------------------------------------------------------------------
// gemm256: C[8192,N] = relu(A[8192,K] @ Bt[N,K]^T + bias), bf16 out.
// 256x256 tile, BK=64, 512 threads = 8 waves (2M x 4N), per-wave out 128x64.
// Requires: M==8192, N==2048, K%128==0, ld==K.
//
// Pipelined body per K-tile T (parity P=T&1; frags af0/bfg0 of tile T were
// read LAST body; af1/bfg1 of tile T read THIS body; af0/bfg0 of T+1 read
// this body's tail into the other named set):
//   DMA x8 (tile T+1 -> buf[1-P])
//   [read af1(T) 8xb128   || MFMA q00 = af0 x bfg0]   <- reads not consumed
//   [read bfg1(T) 4xb128  || MFMA q10 = af1 x bfg0]      by paired cluster
//   vmcnt(0); s_barrier        <- T+1's DMA landed (issued ~1200cyc ago)
//   [read af0(T+1) 8xb128 || MFMA q11 = af1 x bfg1]
//   [read bfg0(T+1) 4xb128|| MFMA q01 = af0 x bfg1]
// Each read region pairs with an MFMA cluster that doesn't consume it ->
// the wave issues ds_reads in matrix-pipe-busy gaps -> LDS/MFMA overlap.
// WAR: pre-BAR reads touch buf[P] only; the DMA crossing that BAR targets
// buf[1-P]; post-BAR reads of buf[1-P] complete before next body's first
// lgkm (q00), i.e., before anyone passes the NEXT BAR that precedes the
// next DMA into buf[1-P]'s parity. One barrier + one vmcnt(0) per K-tile.
// LDS swizzle: slot (row r, chunk s) = global chunk s^(r&7) via pre-swizzled
// global source; conflict-free (verified BANK_CONFLICT=0). NO other vmem in
// the loop (spills would sit in the vmcnt window) — keep regs < 256.
// ---------------------------------------------------------------------------
__global__ __launch_bounds__(512, 2)
void gemm256(const bf16_t* __restrict__ A, const bf16_t* __restrict__ Bt,
             const float* __restrict__ bias, bf16_t* __restrict__ C,
             int N, int K, int ld) {
    constexpr int TSZ  = 256 * 64;           // elts per operand tile (32 KiB)
    constexpr int BUFS = 2 * TSZ;            // A+B per buffer
    __shared__ __align__(16) bf16_t sm[2 * BUFS];   // 128 KiB

    const int tid  = threadIdx.x;
    const int lane = tid & 63;
    const int wave = __builtin_amdgcn_readfirstlane(tid >> 6);
    const int wm = wave >> 2, wn = wave & 3;

    // XCD swizzle: 256 blocks = 32 Mrows x 8 Ncols; each XCD owns 4x8.
    const int lin = blockIdx.x;
    const int xcd = lin & 7, loc = lin >> 3;
    const int m0 = (xcd * 4 + (loc >> 3)) * 256;
    const int n0 = (loc & 7) * 256;

    // ---- staging geometry (1 KiB segment = 8 rows per wave-instruction) ----
    const int lrow = lane >> 3, lch = lane & 7;
    const int sw   = (lch ^ lrow) * 8;       // pre-swizzled source K-chunk
    const bf16_t* Acom = A  + (size_t)(m0 + lrow) * ld + sw;
    const bf16_t* Bcom = Bt + (size_t)(n0 + lrow) * ld + sw;
    int aS[4], bS[4];
    aS[0] = wave;     aS[1] = wave + 16;     // A rows {0-63,128-191}  (mu0)
    aS[2] = wave + 8; aS[3] = wave + 24;     // A rows {64-127,192-255}(mu1)
    const int bb = (wave >> 1) * 8 + (wave & 1) * 2;
    bS[0] = bb;     bS[1] = bb + 1;          // B rows wn*64+[0,32)   (nu0)
    bS[2] = bb + 4; bS[3] = bb + 5;          // B rows wn*64+[32,64)  (nu1)
    const bf16_t* aP[4]; const bf16_t* bP[4];
    int aLo[4], bLo[4];
#pragma unroll
    for (int i = 0; i < 4; ++i) {
        aP[i] = Acom + (size_t)aS[i] * 8 * ld;  aLo[i] = aS[i] * 512;
        bP[i] = Bcom + (size_t)bS[i] * 8 * ld;  bLo[i] = bS[i] * 512;
    }

    // ---- fragment read offsets (elements); XOR depends only on lane&7 ----
    const int r15 = lane & 15, kg = lane >> 4;
    const int xk0 = ( kg      ^ lch) * 8;    // k-chunk for MFMA k-step 0
    const int xk1 = ((kg + 4) ^ lch) * 8;    // k-step 1
    const int aB0 = (wm * 128 + r15) * 64 + xk0;
    const int aB1 = (wm * 128 + r15) * 64 + xk1;
    const int bB0 = (wn * 64  + r15) * 64 + xk0;
    const int bB1 = (wn * 64  + r15) * 64 + xk1;

    floatx4 acc[8][4];
#pragma unroll
    for (int i = 0; i < 8; ++i)
#pragma unroll
        for (int j = 0; j < 4; ++j) acc[i][j] = floatx4{0.f, 0.f, 0.f, 0.f};

    const int nKT = K >> 6;                  // even (K%128==0)

#define G256_RD_A(DST, BUF, MU) \
    _Pragma("unroll") \
    for (int f = 0; f < 4; ++f) { \
        DST[f][0] = *(const bf16x8*)((BUF) + (MU) * 4096 + f * 1024 + aB0); \
        DST[f][1] = *(const bf16x8*)((BUF) + (MU) * 4096 + f * 1024 + aB1); \
    }

#define G256_RD_B(DST, BUF, NU) \
    _Pragma("unroll") \
    for (int g = 0; g < 2; ++g) { \
        DST[g][0] = *(const bf16x8*)((BUF) + (NU) * 2048 + g * 1024 + bB0); \
        DST[g][1] = *(const bf16x8*)((BUF) + (NU) * 2048 + g * 1024 + bB1); \
    }

#define G256_MFMA(AF, BF, I0, J0) \
    __builtin_amdgcn_s_setprio(1); \
    _Pragma("unroll") \
    for (int f = 0; f < 4; ++f) \
    _Pragma("unroll") \
    for (int g = 0; g < 2; ++g) { \
        acc[(I0) + f][(J0) + g] = __builtin_amdgcn_mfma_f32_16x16x32_bf16( \
            AF[f][0], BF[g][0], acc[(I0) + f][(J0) + g], 0, 0, 0); \
        acc[(I0) + f][(J0) + g] = __builtin_amdgcn_mfma_f32_16x16x32_bf16( \
            AF[f][1], BF[g][1], acc[(I0) + f][(J0) + g], 0, 0, 0); \
    } \
    __builtin_amdgcn_s_setprio(0);

// Body for tile T at buffer parity P. CA/CB = this tile's af0/bfg0 (already
// in regs); NXA/NXB = named sets to preload tile T+1's af0/bfg0 into.
#define G256_BODY(CA, CB, NXA, NXB, T, P) do { \
    const bf16_t* bufA = sm + (P) * BUFS; \
    const bf16_t* bufB = bufA + TSZ; \
    bf16_t* nA = sm + (1 - (P)) * BUFS; \
    bf16_t* nB = nA + TSZ; \
    const int tn = ((T) + 1 == nKT) ? 0 : (T) + 1; \
    const size_t ko = (size_t)tn * 64; \
    async_cp16(aP[0] + ko, nA + aLo[0]); \
    async_cp16(aP[1] + ko, nA + aLo[1]); \
    async_cp16(aP[2] + ko, nA + aLo[2]); \
    async_cp16(aP[3] + ko, nA + aLo[3]); \
    async_cp16(bP[0] + ko, nB + bLo[0]); \
    async_cp16(bP[1] + ko, nB + bLo[1]); \
    async_cp16(bP[2] + ko, nB + bLo[2]); \
    async_cp16(bP[3] + ko, nB + bLo[3]); \
    __builtin_amdgcn_sched_barrier(0); \
    G256_RD_A(af1, bufA, 1); \
    G256_MFMA(CA, CB, 0, 0); \
    __builtin_amdgcn_sched_barrier(0); \
    G256_RD_B(bfg1, bufB, 1); \
    G256_MFMA(af1, CB, 4, 0); \
    __builtin_amdgcn_sched_barrier(0); \
    asm volatile("s_waitcnt vmcnt(0)" ::: "memory"); \
    __builtin_amdgcn_s_barrier(); \
    __builtin_amdgcn_sched_barrier(0); \
    G256_RD_A(NXA, nA, 0); \
    G256_MFMA(af1, bfg1, 4, 2); \
    __builtin_amdgcn_sched_barrier(0); \
    G256_RD_B(NXB, nB, 0); \
    G256_MFMA(CA, bfg1, 0, 2); \
    __builtin_amdgcn_sched_barrier(0); \
} while (0)

    bf16x8 af0A[4][2], af0B[4][2], bf0A[2][2], bf0B[2][2];
    bf16x8 af1[4][2], bfg1[2][2];

    // prologue: stage tile 0 -> buf0; gate; preload af0/bfg0 of tile 0
    async_cp16(aP[0], sm + aLo[0]);
    async_cp16(aP[1], sm + aLo[1]);
    async_cp16(aP[2], sm + aLo[2]);
    async_cp16(aP[3], sm + aLo[3]);
    async_cp16(bP[0], sm + TSZ + bLo[0]);
    async_cp16(bP[1], sm + TSZ + bLo[1]);
    async_cp16(bP[2], sm + TSZ + bLo[2]);
    async_cp16(bP[3], sm + TSZ + bLo[3]);
    asm volatile("s_waitcnt vmcnt(0)" ::: "memory");
    __builtin_amdgcn_s_barrier();
    G256_RD_A(af0A, sm, 0);
    G256_RD_B(bf0A, sm + TSZ, 0);

    for (int t = 0; t < nKT; t += 2) {
        G256_BODY(af0A, bf0A, af0B, bf0B, t,     0);
        G256_BODY(af0B, bf0B, af0A, bf0A, t + 1, 1);
    }

    // drain wrap-prefetch LDS-DMA before LDS dealloc at endpgm
    asm volatile("s_waitcnt vmcnt(0)" ::: "memory");

#undef G256_BODY
#undef G256_RD_A
#undef G256_RD_B
#undef G256_MFMA

    // epilogue: C/D layout col=lane&15, row=(lane>>4)*4+reg (m89/m91)
    const int row_l = kg * 4;
#pragma unroll
    for (int j = 0; j < 4; ++j) {
        const int n = n0 + wn * 64 + j * 16 + r15;
        const float bv = bias[n];
#pragma unroll
        for (int i = 0; i < 8; ++i) {
            const int m = m0 + wm * 128 + i * 16 + row_l;
#pragma unroll
            for (int r = 0; r < 4; ++r) {
                float f = acc[i][j][r] + bv;
                f = fmaxf(f, 0.f);
                C[(size_t)(m + r) * N + n] = (bf16_t)f;
            }
        }
    }
}

// ---------------------------------------------------------------------------
// R3 128^2 kernel, kept for d1 (K=64), e3 (N=64 split-K) and d3 (N=1024).
// C[M,N] = act(A[M,K'] @ Bt[N,K']^T + bias), K-segment via blockIdx.y.
// OMODE bit0: bf16 out, bit1: f32 out, bit2: f32 split-K partial.
// ---------------------------------------------------------------------------
template<int BM, int BN, int WM, int WN, int ACT, int OMODE, int GX>
__global__ __launch_bounds__(256)
void gemm_bt(const bf16_t* __restrict__ A, const bf16_t* __restrict__ Bt,
             const float* __restrict__ bias,
             bf16_t* __restrict__ Cb, float* __restrict__ Cf,
             int M, int N, int K, int ld) {
    constexpr int BK = 32;
    constexpr int MI = WM / 16, NI = WN / 16;
    constexpr int WCOLS = BN / WN;
    static_assert((BM / WM) * (BN / WN) == 4, "4 waves");
    constexpr int A_CPW = (BM * BK) / (8 * 64 * 4);
    constexpr int B_CPW = (BN * BK) / (8 * 64 * 4);
    static_assert(A_CPW >= 1 && B_CPW >= 1, "tile too small");
    constexpr int ASZ = BM * BK, BSZ = BN * BK;

    __shared__ bf16_t As[2 * ASZ];
    __shared__ bf16_t Bs[2 * BSZ];

    const int lin = blockIdx.x;
    const int xcd = lin & 7;
    const int loc = lin >> 3;
    const int by  = xcd * 8 + loc / GX;
    const int bx  = loc % GX;

    const int tid  = threadIdx.x;
    const int wave = tid >> 6;
    const int lane = tid & 63;
    const int m0 = by * BM;
    const int n0 = bx * BN;
    const int kz0 = blockIdx.y * K;
    const int wm0 = (wave / WCOLS) * WM;
    const int wn0 = (wave % WCOLS) * WN;
    const int r15 = lane & 15;
    const int kgc = lane >> 4;

    floatx4 acc[MI][NI];
#pragma unroll
    for (int i = 0; i < MI; ++i)
#pragma unroll
        for (int j = 0; j < NI; ++j)
            acc[i][j] = floatx4{0.f, 0.f, 0.f, 0.f};

    const bf16_t* a_src[A_CPW];
    int a_dst[A_CPW];
#pragma unroll
    for (int i = 0; i < A_CPW; ++i) {
        const int cbase = (wave * A_CPW + i) * 64;
        const int chunk = cbase + lane;
        const int row = chunk >> 2;
        const int c8  = (((chunk & 3) - (row >> 1)) & 3) * 8;
        a_src[i] = A + (size_t)(m0 + row) * ld + kz0 + c8;
        a_dst[i] = cbase * 8;
    }
    const bf16_t* b_src[B_CPW];
    int b_dst[B_CPW];
#pragma unroll
    for (int i = 0; i < B_CPW; ++i) {
        const int cbase = (wave * B_CPW + i) * 64;
        const int chunk = cbase + lane;
        const int row = chunk >> 2;
        const int c8  = (((chunk & 3) - (row >> 1)) & 3) * 8;
        b_src[i] = Bt + (size_t)(n0 + row) * ld + kz0 + c8;
        b_dst[i] = cbase * 8;
    }
    int a_off[MI], b_off[NI];
#pragma unroll
    for (int i = 0; i < MI; ++i) {
        const int r = wm0 + i * 16 + r15;
        a_off[i] = r * BK + (((kgc + (r >> 1)) & 3) << 3);
    }
#pragma unroll
    for (int j = 0; j < NI; ++j) {
        const int r = wn0 + j * 16 + r15;
        b_off[j] = r * BK + (((kgc + (r >> 1)) & 3) << 3);
    }

    const int nIter = K / BK;
#pragma unroll
    for (int i = 0; i < A_CPW; ++i) async_cp16(a_src[i], As + a_dst[i]);
#pragma unroll
    for (int i = 0; i < B_CPW; ++i) async_cp16(b_src[i], Bs + b_dst[i]);

    for (int it = 0; it < nIter; ++it) {
        __syncthreads();
        if (it + 1 < nIter) {
            const int kn = (it + 1) * BK;
            const int nb = (it + 1) & 1;
#pragma unroll
            for (int i = 0; i < A_CPW; ++i)
                async_cp16(a_src[i] + kn, As + nb * ASZ + a_dst[i]);
#pragma unroll
            for (int i = 0; i < B_CPW; ++i)
                async_cp16(b_src[i] + kn, Bs + nb * BSZ + b_dst[i]);
        }
        const bf16_t* curA = As + (it & 1) * ASZ;
        const bf16_t* curB = Bs + (it & 1) * BSZ;

        bf16x8 af[MI], bfr[NI];
#pragma unroll
        for (int i = 0; i < MI; ++i)
            af[i] = *(const bf16x8*)(curA + a_off[i]);
#pragma unroll
        for (int j = 0; j < NI; ++j)
            bfr[j] = *(const bf16x8*)(curB + b_off[j]);
#pragma unroll
        for (int i = 0; i < MI; ++i)
#pragma unroll
            for (int j = 0; j < NI; ++j)
                acc[i][j] = __builtin_amdgcn_mfma_f32_16x16x32_bf16(
                    af[i], bfr[j], acc[i][j], 0, 0, 0);
    }

    const int row_l = (lane >> 4) * 4;
#pragma unroll
    for (int j = 0; j < NI; ++j) {
        const int n = n0 + wn0 + j * 16 + r15;
        const float bv = (OMODE & 4) ? 0.f : bias[n];
#pragma unroll
        for (int i = 0; i < MI; ++i) {
            const int m = m0 + wm0 + i * 16 + row_l;
#pragma unroll
            for (int r = 0; r < 4; ++r) {
                float f = acc[i][j][r] + bv;
                if (ACT == 1) f = fmaxf(f, 0.f);
                if (ACT == 2) f = 1.f / (1.f + __expf(-f));
                const size_t idx = (size_t)(m + r) * N + n;
                if (OMODE & 1) Cb[idx] = (bf16_t)f;
                if (OMODE & 2) Cf[idx] = f;
                if (OMODE & 4) Cf[(size_t)blockIdx.y * ((size_t)M * N) + idx] = f;
            }
        }
    }
}

// sum 4 split-K partials + bias -> sigmoid -> out0 (f32) + cb (bf16)
__global__ __launch_bounds__(256)
void e3_reduce(const float* __restrict__ part, const float* __restrict__ be3,
               float* __restrict__ out0, bf16_t* __restrict__ cb) {
    const int t = blockIdx.x * 256 + threadIdx.x;     // 8192*64 threads
    const size_t P = (size_t)8192 * 64;
    float s = part[t] + part[t + P] + part[t + 2 * P] + part[t + 3 * P]
            + be3[t & 63];
    const float f = 1.f / (1.f + __expf(-s));
    out0[t] = f;
    cb[t] = (bf16_t)f;
}

extern "C" void kernel_launch(void* const* d_in, const int* in_sizes, int n_in,
                              void* d_out, int out_size, void* d_ws, size_t ws_size,
                              hipStream_t stream) {
    const float* x   = (const float*)d_in[0];
    const float* We1 = (const float*)d_in[1];
    const float* be1 = (const float*)d_in[2];
    const float* We2 = (const float*)d_in[3];
    const float* be2 = (const float*)d_in[4];
    const float* We3 = (const float*)d_in[5];
    const float* be3 = (const float*)d_in[6];
    const float* Wd1 = (const float*)d_in[7];
    const float* bd1 = (const float*)d_in[8];
    const float* Wd2 = (const float*)d_in[9];
    const float* bd2 = (const float*)d_in[10];
    const float* Wd3 = (const float*)d_in[11];
    const float* bd3 = (const float*)d_in[12];

    char* ws = (char*)d_ws;
    size_t off = 0;
    bf16_t* xb  = (bf16_t*)(ws + off); off += (size_t)8192 * 1024 * 2;
    bf16_t* w1t = (bf16_t*)(ws + off); off += (size_t)2048 * 1024 * 2;
    bf16_t* w2t = (bf16_t*)(ws + off); off += (size_t)2048 * 2048 * 2;
    bf16_t* w3t = (bf16_t*)(ws + off); off += (size_t)64   * 2048 * 2;
    bf16_t* w4t = (bf16_t*)(ws + off); off += (size_t)2048 * 64   * 2;
    bf16_t* w5t = (bf16_t*)(ws + off); off += (size_t)2048 * 2048 * 2;
    bf16_t* w6t = (bf16_t*)(ws + off); off += (size_t)1024 * 2048 * 2;
    bf16_t* ha  = (bf16_t*)(ws + off); off += (size_t)8192 * 2048 * 2;  // hidden ping
    bf16_t* hb  = (bf16_t*)(ws + off); off += (size_t)8192 * 2048 * 2;  // hidden pong
    bf16_t* cb  = (bf16_t*)(ws + off); off += (size_t)8192 * 64   * 2;
    float* e3part = (float*)ha;   // ha dead between e2-consume and d1-write

    float* out0 = (float*)d_out;                    // control_vec [8192,64]
    float* out1 = out0 + (size_t)8192 * 64;         // state_vec   [8192,1024]

    PrepArgs pa;
    pa.x = x; pa.xb = xb;
    pa.w[0] = We1; pa.w[1] = We2; pa.w[2] = We3;
    pa.w[3] = Wd1; pa.w[4] = Wd2; pa.w[5] = Wd3;
    pa.t[0] = w1t; pa.t[1] = w2t; pa.t[2] = w3t;
    pa.t[3] = w4t; pa.t[4] = w5t; pa.t[5] = w6t;
    prep<<<dim3(20736), dim3(32, 8), 0, stream>>>(pa);

    // e1: relu(x @ We1 + be1)   M=8192 N=2048 K=1024  [256^2 8-wave pipeline]
    gemm256<<<dim3(256), dim3(512), 0, stream>>>(xb, w1t, be1, ha, 2048, 1024, 1024);
    // e2: relu(h @ We2 + be2)   K=2048 N=2048
    gemm256<<<dim3(256), dim3(512), 0, stream>>>(ha, w2t, be2, hb, 2048, 2048, 2048);
    // e3: split-K x4 partials (raw fp32), 256 blocks
    gemm_bt<128, 64, 32, 64, 0, 4, 1><<<dim3(64, 4), 256, 0, stream>>>(
        hb, w3t, nullptr, nullptr, e3part, 8192, 64, 512, 2048);
    e3_reduce<<<dim3(2048), 256, 0, stream>>>(e3part, be3, out0, cb);
    // d1: relu(c @ Wd1 + bd1)   K=64 N=2048 (latency-bound; 128^2 path)
    gemm_bt<128, 128, 64, 64, 1, 1, 16><<<dim3(16 * 64), 256, 0, stream>>>(
        cb, w4t, bd1, ha, nullptr, 8192, 2048, 64, 64);
    // d2: relu(h @ Wd2 + bd2)   K=2048 N=2048
    gemm256<<<dim3(256), dim3(512), 0, stream>>>(ha, w5t, bd2, hb, 2048, 2048, 2048);
    // d3: h @ Wd3 + bd3 -> out1 (f32)   K=2048 N=1024 (256^2 would half-fill)
    gemm_bt<128, 128, 64, 64, 0, 2, 8><<<dim3(8 * 64), 256, 0, stream>>>(
        hb, w6t, bd3, nullptr, out1, 8192, 1024, 2048, 2048);
}

// Round 14
// 361.485 us; speedup vs baseline: 1.5714x; 1.5714x over previous
//
#include <hip/hip_runtime.h>
#include <hip/hip_bf16.h>
#include <cstdint>
#include <cstddef>

// ---------------------------------------------------------------------------
// AutoEncoder: x[8192,1024] -> enc(1024->2048->2048->64, relu/relu/sigmoid)
//             -> dec(64->2048->2048->1024, relu/relu/none)
// R17 == R16 == R15 == R14 (GPU unavailable 3 rounds; desk-audited x3).
// Audits: BN_=128 d3 path — B-seg coverage rows 0..127 exact; swizzle
// invariant row&7==lane&7 (wn*32, QOFF both ≡0 mod 8); 96 KiB LDS; frag
// VGPR 40+acc 64; OMODE=2 f32 epilogue coalesced 64B runs; vmcnt(0) gate
// immune to BN-dependent DMA count; e3part/ha aliasing stream-safe; no
// runtime-indexed frag arrays (rule #20); if-constexpr bS fold; grids exact.
// BN=256 path byte-identical to the measured-66us R11 structure.
// R14 vs R13 (568us REGRESSION — spill): R13's ping-pong frag sets needed
// 144 frag VGPRs + 128 acc = 272 > 256 -> scratch spill (WRITE_SIZE 60->353MB,
// MfmaUtil 18.5%). REVERT gemm256 to the R11 single-gate structure (measured
// 66us/dispatch). Schedule-variant scorecard: R10 65.8 ~ R11 66.4 ~ R12 70.6
// -> intra-block LDS/MFMA overlap not achievable at this granularity; stop.
// R14 additions: TAG template (per-layer symbols for profiling); d3 on
// gemm256 BN_=128 (256 blocks full GPU vs old 512 half-occupancy blocks).
// ---------------------------------------------------------------------------

typedef __bf16 bf16_t;
typedef bf16_t bf16x8 __attribute__((ext_vector_type(8)));
typedef bf16_t bf16x4 __attribute__((ext_vector_type(4)));
typedef float  floatx4 __attribute__((ext_vector_type(4)));

__device__ __forceinline__ void async_cp16(const bf16_t* gp, bf16_t* lp) {
    // global->LDS DMA, 16B/lane; LDS dest = wave-uniform base + lane*16
    __builtin_amdgcn_global_load_lds(
        (const __attribute__((address_space(1))) void*)gp,
        (__attribute__((address_space(3))) void*)lp, 16, 0, 0);
}

// ---------------------------------------------------------------------------
// Merged prep: x fp32->bf16 cast + 6 weight transpose+casts in one launch.
// ---------------------------------------------------------------------------
struct PrepArgs {
    const float* x; bf16_t* xb;
    const float* w[6]; bf16_t* t[6];
};

__device__ __forceinline__ void trans_tile(const float* __restrict__ in,
                                           bf16_t* __restrict__ out,
                                           int K, int N, int bx, int by,
                                           int tx, int ty,
                                           float (*tile)[33]) {
    const int n0 = bx * 32, k0 = by * 32;
#pragma unroll
    for (int i = 0; i < 32; i += 8)
        tile[ty + i][tx] = in[(size_t)(k0 + ty + i) * N + n0 + tx];
    __syncthreads();
#pragma unroll
    for (int i = 0; i < 32; i += 8)
        out[(size_t)(n0 + ty + i) * K + k0 + tx] = (bf16_t)tile[tx][ty + i];
}

__global__ __launch_bounds__(256) void prep(PrepArgs a) {
    __shared__ float tile[32][33];
    const int tx = threadIdx.x, ty = threadIdx.y;
    const int b = blockIdx.x;
    if (b < 8192) {                      // x cast: 8192*1024 elts, 4/thread
        const int i = (b * 256 + ty * 32 + tx) * 4;
        const float4 v = *(const float4*)(a.x + i);
        bf16x4 o;
        o[0] = (bf16_t)v.x; o[1] = (bf16_t)v.y;
        o[2] = (bf16_t)v.z; o[3] = (bf16_t)v.w;
        *(bf16x4*)(a.xb + i) = o;
        return;
    }
    int lb = b - 8192;
    if (lb < 2048)      { trans_tile(a.w[0], a.t[0], 1024, 2048, lb % 64, lb / 64, tx, ty, tile); return; }
    lb -= 2048;
    if (lb < 4096)      { trans_tile(a.w[1], a.t[1], 2048, 2048, lb % 64, lb / 64, tx, ty, tile); return; }
    lb -= 4096;
    if (lb < 128)       { trans_tile(a.w[2], a.t[2], 2048, 64,   lb % 2,  lb / 2,  tx, ty, tile); return; }
    lb -= 128;
    if (lb < 128)       { trans_tile(a.w[3], a.t[3], 64,   2048, lb % 64, lb / 64, tx, ty, tile); return; }
    lb -= 128;
    if (lb < 4096)      { trans_tile(a.w[4], a.t[4], 2048, 2048, lb % 64, lb / 64, tx, ty, tile); return; }
    lb -= 4096;
    trans_tile(a.w[5], a.t[5], 2048, 1024, lb % 32, lb / 32, tx, ty, tile);
}

// ---------------------------------------------------------------------------
// gemm256: C[8192,N] = act(A[8192,K] @ Bt[N,K]^T + bias).
// 256xBN_ tile, BK=64, 512 threads = 8 waves (2M x 4N); per-wave out
// 128 x (BN_/4). Requires: M==8192, grid 256 blocks, K%64==0, ld==K.
// OMODE 1: bf16 out (Cb), 2: f32 out (Cf). ACT 0 none, 1 relu.
// TAG: distinct symbol per layer for per-dispatch profiling.
//
// Per K-tile t (R11 single-gate structure, measured 66us @BN=256 e2):
//   vmcnt(0); s_barrier   [tile t's staging landed — issued a K-tile ago]
//   read all fragments (af0, bfg0, af1, bfg1)
//   issue all staging DMAs for tile t+1 -> other buffer
//   4 MFMA clusters (af0xbfg0, af1xbfg0, af1xbfg1, af0xbfg1) @prio1
// LDS swizzle: slot (row r, chunk s) holds global chunk s^(r&7) via
// pre-swizzled global source (linear DMA dest); conflict-free (verified
// SQ_LDS_BANK_CONFLICT=0; row&7 == lane&7 since all other row terms are
// multiples of 8/16). Wrap-prefetch keeps DMA count uniform; drained by
// vmcnt(0) post-loop. NO other vmem ops in the loop; frag VGPR budget must
// stay <= 96 (+128 acc) — R13 lesson: 144 frag VGPRs -> spill disaster.
// ---------------------------------------------------------------------------
template<int BN_, int ACT, int OMODE, int TAG>
__global__ __launch_bounds__(512, 2)
void gemm256(const bf16_t* __restrict__ A, const bf16_t* __restrict__ Bt,
             const float* __restrict__ bias,
             bf16_t* __restrict__ Cb, float* __restrict__ Cf,
             int N, int K, int ld) {
    constexpr int WN_   = BN_ / 4;            // per-wave N extent: 64 or 32
    constexpr int NI    = BN_ / 64;           // acc cols: 4 or 2
    constexpr int GQ    = NI / 2;             // frags per B-quadrant: 2 or 1
    constexpr int BSEGW = BN_ / 64;           // B 8-row segs per wave: 4 or 2
    constexpr int QOFF  = (WN_ / 2) * 64;     // B quadrant LDS offset (elts)
    constexpr int TSZA  = 256 * 64;
    constexpr int TSZB  = BN_ * 64;
    constexpr int BUFS  = TSZA + TSZB;
    __shared__ __align__(16) bf16_t sm[2 * BUFS];   // 128 KiB (BN=256) / 96 KiB

    const int tid  = threadIdx.x;
    const int lane = tid & 63;
    const int wave = __builtin_amdgcn_readfirstlane(tid >> 6);
    const int wm = wave >> 2, wn = wave & 3;

    // XCD swizzle: 256 blocks = 32 Mrows x 8 Ncols; each XCD owns 4x8.
    const int lin = blockIdx.x;
    const int xcd = lin & 7, loc = lin >> 3;
    const int m0 = (xcd * 4 + (loc >> 3)) * 256;
    const int n0 = (loc & 7) * BN_;

    // ---- staging geometry (1 KiB segment = 8 rows per wave-instruction) ----
    const int lrow = lane >> 3, lch = lane & 7;
    const int sw   = (lch ^ lrow) * 8;       // pre-swizzled source K-chunk
    const bf16_t* Acom = A  + (size_t)(m0 + lrow) * ld + sw;
    const bf16_t* Bcom = Bt + (size_t)(n0 + lrow) * ld + sw;
    int aS[4];
    aS[0] = wave;     aS[1] = wave + 16;     // A rows {0-63,128-191}  (mu0)
    aS[2] = wave + 8; aS[3] = wave + 24;     // A rows {64-127,192-255}(mu1)
    int bS[BSEGW];
    if constexpr (BN_ == 256) {
        const int bb = (wave >> 1) * 8 + (wave & 1) * 2;
        bS[0] = bb;     bS[1] = bb + 1;      // rows wn*64+[0,32)  (nu0)
        bS[2] = bb + 4; bS[3] = bb + 5;      // rows wn*64+[32,64) (nu1)
    } else {
        bS[0] = 2 * wave; bS[1] = 2 * wave + 1;   // rows 16w..16w+15
    }
    const bf16_t* aP[4]; int aLo[4];
#pragma unroll
    for (int i = 0; i < 4; ++i) {
        aP[i] = Acom + (size_t)aS[i] * 8 * ld;  aLo[i] = aS[i] * 512;
    }
    const bf16_t* bP[BSEGW]; int bLo[BSEGW];
#pragma unroll
    for (int i = 0; i < BSEGW; ++i) {
        bP[i] = Bcom + (size_t)bS[i] * 8 * ld;  bLo[i] = bS[i] * 512;
    }

    // ---- fragment read offsets (elements); XOR depends only on lane&7 ----
    const int r15 = lane & 15, kg = lane >> 4;
    const int xk0 = ( kg      ^ lch) * 8;    // k-chunk for MFMA k-step 0
    const int xk1 = ((kg + 4) ^ lch) * 8;    // k-step 1
    const int aB0 = (wm * 128 + r15) * 64 + xk0;
    const int aB1 = (wm * 128 + r15) * 64 + xk1;
    const int bB0 = (wn * WN_ + r15) * 64 + xk0;
    const int bB1 = (wn * WN_ + r15) * 64 + xk1;

    floatx4 acc[8][NI];
#pragma unroll
    for (int i = 0; i < 8; ++i)
#pragma unroll
        for (int j = 0; j < NI; ++j) acc[i][j] = floatx4{0.f, 0.f, 0.f, 0.f};

    const int nKT = K >> 6;

    // prologue: tile 0 into buf 0
#pragma unroll
    for (int i = 0; i < 4; ++i)     async_cp16(aP[i], sm + aLo[i]);
#pragma unroll
    for (int i = 0; i < BSEGW; ++i) async_cp16(bP[i], sm + TSZA + bLo[i]);

    bf16x8 af0[4][2], af1[4][2], bfg0[GQ][2], bfg1[GQ][2];
    for (int t = 0; t < nKT; ++t) {
        const bf16_t* bufA = sm + (t & 1) * BUFS;
        const bf16_t* bufB = bufA + TSZA;
        bf16_t* nA = sm + ((t + 1) & 1) * BUFS;
        bf16_t* nB = nA + TSZA;
        const int tn = (t + 1 == nKT) ? 0 : t + 1;   // wrap prefetch (uniform)
        const size_t ko = (size_t)tn * 64;

        // ---- single gate per K-tile ----
        asm volatile("s_waitcnt vmcnt(0)" ::: "memory");
        __builtin_amdgcn_s_barrier();
        __builtin_amdgcn_sched_barrier(0);

        // ---- read all fragments (consumption order) ----
#pragma unroll
        for (int f = 0; f < 4; ++f) {
            af0[f][0] = *(const bf16x8*)(bufA + f * 1024 + aB0);
            af0[f][1] = *(const bf16x8*)(bufA + f * 1024 + aB1);
        }
#pragma unroll
        for (int g = 0; g < GQ; ++g) {
            bfg0[g][0] = *(const bf16x8*)(bufB + g * 1024 + bB0);
            bfg0[g][1] = *(const bf16x8*)(bufB + g * 1024 + bB1);
        }
#pragma unroll
        for (int f = 0; f < 4; ++f) {
            af1[f][0] = *(const bf16x8*)(bufA + 4096 + f * 1024 + aB0);
            af1[f][1] = *(const bf16x8*)(bufA + 4096 + f * 1024 + aB1);
        }
#pragma unroll
        for (int g = 0; g < GQ; ++g) {
            bfg1[g][0] = *(const bf16x8*)(bufB + QOFF + g * 1024 + bB0);
            bfg1[g][1] = *(const bf16x8*)(bufB + QOFF + g * 1024 + bB1);
        }

        // ---- issue all staging for tile t+1 (into the other buffer) ----
#pragma unroll
        for (int i = 0; i < 4; ++i)     async_cp16(aP[i] + ko, nA + aLo[i]);
#pragma unroll
        for (int i = 0; i < BSEGW; ++i) async_cp16(bP[i] + ko, nB + bLo[i]);

        // ---- 4 MFMA clusters; compiler inserts incremental lgkmcnt ----
#define G256_MFMA(AF, BF, I0, J0) \
        __builtin_amdgcn_s_setprio(1); \
        _Pragma("unroll") \
        for (int f = 0; f < 4; ++f) \
        _Pragma("unroll") \
        for (int g = 0; g < GQ; ++g) { \
            acc[(I0) + f][(J0) + g] = __builtin_amdgcn_mfma_f32_16x16x32_bf16( \
                AF[f][0], BF[g][0], acc[(I0) + f][(J0) + g], 0, 0, 0); \
            acc[(I0) + f][(J0) + g] = __builtin_amdgcn_mfma_f32_16x16x32_bf16( \
                AF[f][1], BF[g][1], acc[(I0) + f][(J0) + g], 0, 0, 0); \
        } \
        __builtin_amdgcn_s_setprio(0);

        G256_MFMA(af0, bfg0, 0, 0);
        G256_MFMA(af1, bfg0, 4, 0);
        G256_MFMA(af1, bfg1, 4, GQ);
        G256_MFMA(af0, bfg1, 0, GQ);
#undef G256_MFMA
    }

    // drain wrap-prefetch LDS-DMA before LDS dealloc at endpgm
    asm volatile("s_waitcnt vmcnt(0)" ::: "memory");

    // epilogue: C/D layout col=lane&15, row=(lane>>4)*4+reg (m89/m91)
    const int row_l = kg * 4;
#pragma unroll
    for (int j = 0; j < NI; ++j) {
        const int n = n0 + wn * WN_ + j * 16 + r15;
        const float bv = bias[n];
#pragma unroll
        for (int i = 0; i < 8; ++i) {
            const int m = m0 + wm * 128 + i * 16 + row_l;
#pragma unroll
            for (int r = 0; r < 4; ++r) {
                float f = acc[i][j][r] + bv;
                if (ACT == 1) f = fmaxf(f, 0.f);
                const size_t idx = (size_t)(m + r) * N + n;
                if (OMODE & 1) Cb[idx] = (bf16_t)f;
                if (OMODE & 2) Cf[idx] = f;
            }
        }
    }
}

// ---------------------------------------------------------------------------
// R3 128^2 kernel, kept for d1 (K=64) and e3 (N=64 split-K).
// C[M,N] = act(A[M,K'] @ Bt[N,K']^T + bias), K-segment via blockIdx.y.
// OMODE bit0: bf16 out, bit1: f32 out, bit2: f32 split-K partial.
// ---------------------------------------------------------------------------
template<int BM, int BN, int WM, int WN, int ACT, int OMODE, int GX>
__global__ __launch_bounds__(256)
void gemm_bt(const bf16_t* __restrict__ A, const bf16_t* __restrict__ Bt,
             const float* __restrict__ bias,
             bf16_t* __restrict__ Cb, float* __restrict__ Cf,
             int M, int N, int K, int ld) {
    constexpr int BK = 32;
    constexpr int MI = WM / 16, NI = WN / 16;
    constexpr int WCOLS = BN / WN;
    static_assert((BM / WM) * (BN / WN) == 4, "4 waves");
    constexpr int A_CPW = (BM * BK) / (8 * 64 * 4);
    constexpr int B_CPW = (BN * BK) / (8 * 64 * 4);
    static_assert(A_CPW >= 1 && B_CPW >= 1, "tile too small");
    constexpr int ASZ = BM * BK, BSZ = BN * BK;

    __shared__ bf16_t As[2 * ASZ];
    __shared__ bf16_t Bs[2 * BSZ];

    const int lin = blockIdx.x;
    const int xcd = lin & 7;
    const int loc = lin >> 3;
    const int by  = xcd * 8 + loc / GX;
    const int bx  = loc % GX;

    const int tid  = threadIdx.x;
    const int wave = tid >> 6;
    const int lane = tid & 63;
    const int m0 = by * BM;
    const int n0 = bx * BN;
    const int kz0 = blockIdx.y * K;
    const int wm0 = (wave / WCOLS) * WM;
    const int wn0 = (wave % WCOLS) * WN;
    const int r15 = lane & 15;
    const int kgc = lane >> 4;

    floatx4 acc[MI][NI];
#pragma unroll
    for (int i = 0; i < MI; ++i)
#pragma unroll
        for (int j = 0; j < NI; ++j)
            acc[i][j] = floatx4{0.f, 0.f, 0.f, 0.f};

    const bf16_t* a_src[A_CPW];
    int a_dst[A_CPW];
#pragma unroll
    for (int i = 0; i < A_CPW; ++i) {
        const int cbase = (wave * A_CPW + i) * 64;
        const int chunk = cbase + lane;
        const int row = chunk >> 2;
        const int c8  = (((chunk & 3) - (row >> 1)) & 3) * 8;
        a_src[i] = A + (size_t)(m0 + row) * ld + kz0 + c8;
        a_dst[i] = cbase * 8;
    }
    const bf16_t* b_src[B_CPW];
    int b_dst[B_CPW];
#pragma unroll
    for (int i = 0; i < B_CPW; ++i) {
        const int cbase = (wave * B_CPW + i) * 64;
        const int chunk = cbase + lane;
        const int row = chunk >> 2;
        const int c8  = (((chunk & 3) - (row >> 1)) & 3) * 8;
        b_src[i] = Bt + (size_t)(n0 + row) * ld + kz0 + c8;
        b_dst[i] = cbase * 8;
    }
    int a_off[MI], b_off[NI];
#pragma unroll
    for (int i = 0; i < MI; ++i) {
        const int r = wm0 + i * 16 + r15;
        a_off[i] = r * BK + (((kgc + (r >> 1)) & 3) << 3);
    }
#pragma unroll
    for (int j = 0; j < NI; ++j) {
        const int r = wn0 + j * 16 + r15;
        b_off[j] = r * BK + (((kgc + (r >> 1)) & 3) << 3);
    }

    const int nIter = K / BK;
#pragma unroll
    for (int i = 0; i < A_CPW; ++i) async_cp16(a_src[i], As + a_dst[i]);
#pragma unroll
    for (int i = 0; i < B_CPW; ++i) async_cp16(b_src[i], Bs + b_dst[i]);

    for (int it = 0; it < nIter; ++it) {
        __syncthreads();
        if (it + 1 < nIter) {
            const int kn = (it + 1) * BK;
            const int nb = (it + 1) & 1;
#pragma unroll
            for (int i = 0; i < A_CPW; ++i)
                async_cp16(a_src[i] + kn, As + nb * ASZ + a_dst[i]);
#pragma unroll
            for (int i = 0; i < B_CPW; ++i)
                async_cp16(b_src[i] + kn, Bs + nb * BSZ + b_dst[i]);
        }
        const bf16_t* curA = As + (it & 1) * ASZ;
        const bf16_t* curB = Bs + (it & 1) * BSZ;

        bf16x8 af[MI], bfr[NI];
#pragma unroll
        for (int i = 0; i < MI; ++i)
            af[i] = *(const bf16x8*)(curA + a_off[i]);
#pragma unroll
        for (int j = 0; j < NI; ++j)
            bfr[j] = *(const bf16x8*)(curB + b_off[j]);
#pragma unroll
        for (int i = 0; i < MI; ++i)
#pragma unroll
            for (int j = 0; j < NI; ++j)
                acc[i][j] = __builtin_amdgcn_mfma_f32_16x16x32_bf16(
                    af[i], bfr[j], acc[i][j], 0, 0, 0);
    }

    const int row_l = (lane >> 4) * 4;
#pragma unroll
    for (int j = 0; j < NI; ++j) {
        const int n = n0 + wn0 + j * 16 + r15;
        const float bv = (OMODE & 4) ? 0.f : bias[n];
#pragma unroll
        for (int i = 0; i < MI; ++i) {
            const int m = m0 + wm0 + i * 16 + row_l;
#pragma unroll
            for (int r = 0; r < 4; ++r) {
                float f = acc[i][j][r] + bv;
                if (ACT == 1) f = fmaxf(f, 0.f);
                if (ACT == 2) f = 1.f / (1.f + __expf(-f));
                const size_t idx = (size_t)(m + r) * N + n;
                if (OMODE & 1) Cb[idx] = (bf16_t)f;
                if (OMODE & 2) Cf[idx] = f;
                if (OMODE & 4) Cf[(size_t)blockIdx.y * ((size_t)M * N) + idx] = f;
            }
        }
    }
}

// sum 4 split-K partials + bias -> sigmoid -> out0 (f32) + cb (bf16)
__global__ __launch_bounds__(256)
void e3_reduce(const float* __restrict__ part, const float* __restrict__ be3,
               float* __restrict__ out0, bf16_t* __restrict__ cb) {
    const int t = blockIdx.x * 256 + threadIdx.x;     // 8192*64 threads
    const size_t P = (size_t)8192 * 64;
    float s = part[t] + part[t + P] + part[t + 2 * P] + part[t + 3 * P]
            + be3[t & 63];
    const float f = 1.f / (1.f + __expf(-s));
    out0[t] = f;
    cb[t] = (bf16_t)f;
}

extern "C" void kernel_launch(void* const* d_in, const int* in_sizes, int n_in,
                              void* d_out, int out_size, void* d_ws, size_t ws_size,
                              hipStream_t stream) {
    const float* x   = (const float*)d_in[0];
    const float* We1 = (const float*)d_in[1];
    const float* be1 = (const float*)d_in[2];
    const float* We2 = (const float*)d_in[3];
    const float* be2 = (const float*)d_in[4];
    const float* We3 = (const float*)d_in[5];
    const float* be3 = (const float*)d_in[6];
    const float* Wd1 = (const float*)d_in[7];
    const float* bd1 = (const float*)d_in[8];
    const float* Wd2 = (const float*)d_in[9];
    const float* bd2 = (const float*)d_in[10];
    const float* Wd3 = (const float*)d_in[11];
    const float* bd3 = (const float*)d_in[12];

    char* ws = (char*)d_ws;
    size_t off = 0;
    bf16_t* xb  = (bf16_t*)(ws + off); off += (size_t)8192 * 1024 * 2;
    bf16_t* w1t = (bf16_t*)(ws + off); off += (size_t)2048 * 1024 * 2;
    bf16_t* w2t = (bf16_t*)(ws + off); off += (size_t)2048 * 2048 * 2;
    bf16_t* w3t = (bf16_t*)(ws + off); off += (size_t)64   * 2048 * 2;
    bf16_t* w4t = (bf16_t*)(ws + off); off += (size_t)2048 * 64   * 2;
    bf16_t* w5t = (bf16_t*)(ws + off); off += (size_t)2048 * 2048 * 2;
    bf16_t* w6t = (bf16_t*)(ws + off); off += (size_t)1024 * 2048 * 2;
    bf16_t* ha  = (bf16_t*)(ws + off); off += (size_t)8192 * 2048 * 2;  // hidden ping
    bf16_t* hb  = (bf16_t*)(ws + off); off += (size_t)8192 * 2048 * 2;  // hidden pong
    bf16_t* cb  = (bf16_t*)(ws + off); off += (size_t)8192 * 64   * 2;
    float* e3part = (float*)ha;   // ha dead between e2-consume and d1-write

    float* out0 = (float*)d_out;                    // control_vec [8192,64]
    float* out1 = out0 + (size_t)8192 * 64;         // state_vec   [8192,1024]

    PrepArgs pa;
    pa.x = x; pa.xb = xb;
    pa.w[0] = We1; pa.w[1] = We2; pa.w[2] = We3;
    pa.w[3] = Wd1; pa.w[4] = Wd2; pa.w[5] = Wd3;
    pa.t[0] = w1t; pa.t[1] = w2t; pa.t[2] = w3t;
    pa.t[3] = w4t; pa.t[4] = w5t; pa.t[5] = w6t;
    prep<<<dim3(20736), dim3(32, 8), 0, stream>>>(pa);

    // e1: relu(x @ We1 + be1)   M=8192 N=2048 K=1024
    gemm256<256, 1, 1, 1><<<dim3(256), dim3(512), 0, stream>>>(
        xb, w1t, be1, ha, nullptr, 2048, 1024, 1024);
    // e2: relu(h @ We2 + be2)   K=2048 N=2048
    gemm256<256, 1, 1, 2><<<dim3(256), dim3(512), 0, stream>>>(
        ha, w2t, be2, hb, nullptr, 2048, 2048, 2048);
    // e3: split-K x4 partials (raw fp32), 256 blocks
    gemm_bt<128, 64, 32, 64, 0, 4, 1><<<dim3(64, 4), 256, 0, stream>>>(
        hb, w3t, nullptr, nullptr, e3part, 8192, 64, 512, 2048);
    e3_reduce<<<dim3(2048), 256, 0, stream>>>(e3part, be3, out0, cb);
    // d1: relu(c @ Wd1 + bd1)   K=64 N=2048 (latency-bound; 128^2 path)
    gemm_bt<128, 128, 64, 64, 1, 1, 16><<<dim3(16 * 64), 256, 0, stream>>>(
        cb, w4t, bd1, ha, nullptr, 8192, 2048, 64, 64);
    // d2: relu(h @ Wd2 + bd2)   K=2048 N=2048
    gemm256<256, 1, 1, 3><<<dim3(256), dim3(512), 0, stream>>>(
        ha, w5t, bd2, hb, nullptr, 2048, 2048, 2048);
    // d3: h @ Wd3 + bd3 -> out1 (f32)   K=2048 N=1024  [256x128 tile, 256 blk]
    gemm256<128, 0, 2, 4><<<dim3(256), dim3(512), 0, stream>>>(
        hb, w6t, bd3, nullptr, out1, 1024, 2048, 2048);
}